// Round 4
// baseline (238.406 us; speedup 1.0000x reference)
//
#include <hip/hip_runtime.h>
#include <hip/hip_bf16.h>
#include <hip/hip_fp16.h>
#include <math.h>

#define N_NODES 10000
#define DIM 128
#define N_EDGES 640000
#define BN_EPS 1e-3f

#define MSG_MFMA_BLOCKS 313   // ceil(10000 / 32)
#define HIST4_BLOCKS 1250     // 640000 / (128*4)
#define SCAT_BLOCKS 625       // 640000 / (256*4)

typedef _Float16 half8 __attribute__((ext_vector_type(8)));
typedef float f32x4 __attribute__((ext_vector_type(4)));

__device__ __forceinline__ float gelu_exact(float x) {
  return 0.5f * x * (1.0f + erff(x * 0.70710678f));
}

// Swizzled per-wave LDS tile: [16 rows][128 cols] f16, row stride 256 B.
// XOR-swizzle byte ^ ((row&7)<<4) kills the 16-way ds_read_b128 bank conflict.
__device__ __forceinline__ int lds_swz(int row, int colbyte) {
  return ((row * 256 + colbyte) ^ ((row & 7) << 4));
}

struct FoldAll {
  const float* g[4];
  const float* bb[4];
  const float* m[4];
  const float* v[4];
  const float* W[4];
  const float* bias[4];
  _Float16* pk[4];
  float* bf[4];
  int din[4];
  int S[4];  // K/32
};

// grid = 54 blocks x 256 thr.
// blocks [0,40): pack W fragments (f16, B-frag layout, BN-scale folded in)
//   W1: blocks 0-7, W2: 8-15, U1: 16-31, U2: 32-39.
// blocks [40,44): folded bias for param (blk-40): bf = bias + t @ W.
// blocks [44,54): zero hist (int4).
__global__ __launch_bounds__(256) void fold_pack_kernel(FoldAll fa, int* __restrict__ hist) {
  int b = blockIdx.x, t = threadIdx.x;
  if (b >= 44) {
    int tid = (b - 44) * 256 + t;
    if (tid < 2500) reinterpret_cast<int4*>(hist)[tid] = make_int4(0, 0, 0, 0);
    return;
  }
  if (b >= 40) {
    int p = b - 40;
    int din = fa.din[p];
    const float* W = fa.W[p];
    __shared__ float t_sh[256];
    __shared__ float bpart[128];
    for (int k = t; k < din; k += 256) {
      float sc = fa.g[p][k] * rsqrtf(fa.v[p][k] + BN_EPS);
      t_sh[k] = fa.bb[p][k] - fa.m[p][k] * sc;
    }
    __syncthreads();
    int j = t & 127, kh = t >> 7;
    int half = din >> 1;
    float acc = 0.f;
    for (int k = kh * half; k < (kh + 1) * half; ++k)
      acc = fmaf(t_sh[k], W[k * 128 + j], acc);
    if (kh == 1) bpart[j] = acc;
    __syncthreads();
    if (kh == 0) fa.bf[p][j] = acc + bpart[j] + fa.bias[p][j];
    return;
  }
  // pack
  int p, lf;
  if (b < 8)       { p = 0; lf = b * 256 + t; }
  else if (b < 16) { p = 1; lf = (b - 8) * 256 + t; }
  else if (b < 32) { p = 2; lf = (b - 16) * 256 + t; }
  else             { p = 3; lf = (b - 32) * 256 + t; }
  int S = fa.S[p];
  int l = lf & 63;
  int fs = lf >> 6;        // = s*8 + f
  int f = fs & 7, s = fs >> 3;
  if (s >= S) return;
  const float* W = fa.W[p];
  const float* g = fa.g[p];
  const float* v = fa.v[p];
  int k0 = s * 32 + (l >> 4) * 8;
  int col = f * 16 + (l & 15);
  half8 h;
#pragma unroll
  for (int i = 0; i < 8; ++i) {
    int k = k0 + i;
    float sc = g[k] * rsqrtf(v[k] + BN_EPS);
    h[i] = (_Float16)(sc * W[k * 128 + col]);
  }
  *reinterpret_cast<half8*>(fa.pk[p] + (size_t)lf * 8) = h;
}

// Blocks [0, MSG_MFMA_BLOCKS): per-node message via f16 MFMA.
//   2 waves/block, 16 rows/wave, full 128 cols, K=128 (4 steps).
// Blocks [MSG_MFMA_BLOCKS, +HIST4_BLOCKS): degree histogram (4 edges/thr).
__global__ __launch_bounds__(128) void msg_mfma_hist_kernel(
    const float* __restrict__ x,
    const _Float16* __restrict__ W1pk, const float* __restrict__ b1f,
    const _Float16* __restrict__ W2pk, const float* __restrict__ b2f,
    _Float16* __restrict__ M,
    const int* __restrict__ node_idx, int* __restrict__ hist) {
  int bx = blockIdx.x, t = threadIdx.x;
  if (bx >= MSG_MFMA_BLOCKS) {
    int base = ((bx - MSG_MFMA_BLOCKS) * 128 + t) * 4;
    int4 vv = *reinterpret_cast<const int4*>(&node_idx[base]);
    atomicAdd(&hist[vv.x], 1);
    atomicAdd(&hist[vv.y], 1);
    atomicAdd(&hist[vv.z], 1);
    atomicAdd(&hist[vv.w], 1);
    return;
  }
  __shared__ char lds_raw[2 * 4096];
  int wid = t >> 6, lane = t & 63;
  int r = lane & 15, g = lane >> 4;
  int row0 = bx * 32 + wid * 16;
  char* lbase = lds_raw + wid * 4096;

  int arow = row0 + r;
  if (arow > N_NODES - 1) arow = N_NODES - 1;
  const float* xp = x + (size_t)arow * DIM;

  half8 a[4];
#pragma unroll
  for (int s = 0; s < 4; ++s) {
    float4 lo = *reinterpret_cast<const float4*>(xp + s * 32 + g * 8);
    float4 hi = *reinterpret_cast<const float4*>(xp + s * 32 + g * 8 + 4);
    half8 h;
    h[0] = (_Float16)lo.x; h[1] = (_Float16)lo.y; h[2] = (_Float16)lo.z; h[3] = (_Float16)lo.w;
    h[4] = (_Float16)hi.x; h[5] = (_Float16)hi.y; h[6] = (_Float16)hi.z; h[7] = (_Float16)hi.w;
    a[s] = h;
  }

  f32x4 zero = {0.f, 0.f, 0.f, 0.f};
  f32x4 acc[8];
#pragma unroll
  for (int f = 0; f < 8; ++f) acc[f] = zero;
#pragma unroll
  for (int f = 0; f < 8; ++f)
#pragma unroll
    for (int s = 0; s < 4; ++s) {
      half8 bfrag = *reinterpret_cast<const half8*>(W1pk + (size_t)((s * 8 + f) * 64 + lane) * 8);
      acc[f] = __builtin_amdgcn_mfma_f32_16x16x32_f16(a[s], bfrag, acc[f], 0, 0, 0);
    }

  // gelu + bias -> swizzled LDS (f16), per-wave region (no barrier needed)
#pragma unroll
  for (int f = 0; f < 8; ++f) {
    int col = f * 16 + r;
    float bv = b1f[col];
#pragma unroll
    for (int j = 0; j < 4; ++j) {
      int rl = g * 4 + j;
      float gv = gelu_exact(acc[f][j] + bv);
      *reinterpret_cast<_Float16*>(lbase + lds_swz(rl, col * 2)) = (_Float16)gv;
    }
  }

  half8 a2[4];
#pragma unroll
  for (int s = 0; s < 4; ++s)
    a2[s] = *reinterpret_cast<const half8*>(lbase + lds_swz(r, (s * 32 + g * 8) * 2));

  f32x4 acc2[8];
#pragma unroll
  for (int f = 0; f < 8; ++f) acc2[f] = zero;
#pragma unroll
  for (int f = 0; f < 8; ++f)
#pragma unroll
    for (int s = 0; s < 4; ++s) {
      half8 bfrag = *reinterpret_cast<const half8*>(W2pk + (size_t)((s * 8 + f) * 64 + lane) * 8);
      acc2[f] = __builtin_amdgcn_mfma_f32_16x16x32_f16(a2[s], bfrag, acc2[f], 0, 0, 0);
    }

#pragma unroll
  for (int f = 0; f < 8; ++f) {
    int col = f * 16 + r;
    float bv = b2f[col];
#pragma unroll
    for (int j = 0; j < 4; ++j) {
      int grow = row0 + g * 4 + j;
      if (grow < N_NODES)
        M[(size_t)grow * DIM + col] = (_Float16)gelu_exact(acc2[f][j] + bv);
    }
  }
}

// One block, 256 threads, each owns 40 contiguous elements.
__global__ __launch_bounds__(256) void scan_kernel(const int* __restrict__ hist,
                                                   int* __restrict__ row_start,
                                                   int* __restrict__ cursor, int n) {
  const int PER = 40;
  __shared__ int sums[256];
  int t = threadIdx.x;
  int i0 = t * PER;
  int total = 0;
  for (int i = 0; i < PER; ++i) {
    int idx = i0 + i;
    total += (idx < n) ? hist[idx] : 0;
  }
  sums[t] = total;
  __syncthreads();
  for (int off = 1; off < 256; off <<= 1) {
    int v = (t >= off) ? sums[t - off] : 0;
    __syncthreads();
    sums[t] += v;
    __syncthreads();
  }
  int running = sums[t] - total;
  for (int i = 0; i < PER; ++i) {
    int idx = i0 + i;
    if (idx < n) {
      row_start[idx] = running;
      cursor[idx] = running;
      running += hist[idx];
    }
  }
  if (t == 255) row_start[n] = sums[255];
}

// Pack (nbr, weight) into uint2 per edge, CSR-ordered. 4 edges/thread.
__global__ __launch_bounds__(256) void scatter_kernel(
    const int* __restrict__ node_idx, const int* __restrict__ nbr_idx,
    const float* __restrict__ ew, int* __restrict__ cursor,
    uint2* __restrict__ edge_s) {
  int base = (blockIdx.x * 256 + threadIdx.x) * 4;
  if (base >= N_EDGES) return;
  int4 ni = *reinterpret_cast<const int4*>(&node_idx[base]);
  int4 nb = *reinterpret_cast<const int4*>(&nbr_idx[base]);
  float4 wv = *reinterpret_cast<const float4*>(&ew[base]);
  int p0 = atomicAdd(&cursor[ni.x], 1);
  edge_s[p0] = make_uint2((unsigned)nb.x, __float_as_uint(wv.x));
  int p1 = atomicAdd(&cursor[ni.y], 1);
  edge_s[p1] = make_uint2((unsigned)nb.y, __float_as_uint(wv.y));
  int p2 = atomicAdd(&cursor[ni.z], 1);
  edge_s[p2] = make_uint2((unsigned)nb.z, __float_as_uint(wv.z));
  int p3 = atomicAdd(&cursor[ni.w], 1);
  edge_s[p3] = make_uint2((unsigned)nb.w, __float_as_uint(wv.w));
}

// agg[i] = (sum over CSR row i of w_e * M[nbr_e]) / max(cnt,1)
__global__ __launch_bounds__(256) void spmm_kernel(
    const int* __restrict__ row_start, const uint2* __restrict__ edge_s,
    const __half* __restrict__ M, float* __restrict__ agg) {
  __shared__ float4 red4[8][32];
  int i = blockIdx.x;
  int t = threadIdx.x;
  int cg = t & 31;
  int slice = t >> 5;
  int s = row_start[i];
  int e_end = row_start[i + 1];

  float a0 = 0.f, a1 = 0.f, a2 = 0.f, a3 = 0.f;
  int e = s + slice;
  if (e < e_end) {
    uint2 pk = edge_s[e];
    for (; e < e_end; e += 8) {
      int en = e + 8;
      uint2 nxt = (en < e_end) ? edge_s[en] : pk;
      unsigned nbr = pk.x;
      float w = __uint_as_float(pk.y);
      uint2 raw = *reinterpret_cast<const uint2*>(M + (size_t)nbr * DIM + cg * 4);
      __half2 h01 = *reinterpret_cast<__half2*>(&raw.x);
      __half2 h23 = *reinterpret_cast<__half2*>(&raw.y);
      float2 f01 = __half22float2(h01);
      float2 f23 = __half22float2(h23);
      a0 = fmaf(w, f01.x, a0);
      a1 = fmaf(w, f01.y, a1);
      a2 = fmaf(w, f23.x, a2);
      a3 = fmaf(w, f23.y, a3);
      pk = nxt;
    }
  }
  red4[slice][cg] = make_float4(a0, a1, a2, a3);
  __syncthreads();

  if (t < 128) {
    const float* redf = (const float*)red4;
    float acc = 0.f;
#pragma unroll
    for (int sl = 0; sl < 8; ++sl) acc += redf[sl * 128 + t];
    int cnt = e_end - s;
    agg[(size_t)i * DIM + t] = acc / (float)(cnt > 0 ? cnt : 1);
  }
}

// update: out = gelu(gelu([x,agg]@U1+bu1)@U2+bu2), f16 MFMA, K1=256.
__global__ __launch_bounds__(128) void update_mfma_kernel(
    const float* __restrict__ x, const float* __restrict__ agg,
    const _Float16* __restrict__ U1pk, const float* __restrict__ bu1,
    const _Float16* __restrict__ U2pk, const float* __restrict__ bu2,
    float* __restrict__ out) {
  __shared__ char lds_raw[2 * 4096];
  int t = threadIdx.x;
  int wid = t >> 6, lane = t & 63;
  int r = lane & 15, g = lane >> 4;
  int row0 = blockIdx.x * 32 + wid * 16;
  char* lbase = lds_raw + wid * 4096;

  int arow = row0 + r;
  if (arow > N_NODES - 1) arow = N_NODES - 1;
  const float* xp = x + (size_t)arow * DIM;
  const float* ap = agg + (size_t)arow * DIM;

  half8 a[8];
#pragma unroll
  for (int s = 0; s < 8; ++s) {
    const float* src = (s < 4) ? (xp + s * 32 + g * 8) : (ap + (s - 4) * 32 + g * 8);
    float4 lo = *reinterpret_cast<const float4*>(src);
    float4 hi = *reinterpret_cast<const float4*>(src + 4);
    half8 h;
    h[0] = (_Float16)lo.x; h[1] = (_Float16)lo.y; h[2] = (_Float16)lo.z; h[3] = (_Float16)lo.w;
    h[4] = (_Float16)hi.x; h[5] = (_Float16)hi.y; h[6] = (_Float16)hi.z; h[7] = (_Float16)hi.w;
    a[s] = h;
  }

  f32x4 zero = {0.f, 0.f, 0.f, 0.f};
  f32x4 acc[8];
#pragma unroll
  for (int f = 0; f < 8; ++f) acc[f] = zero;
#pragma unroll
  for (int f = 0; f < 8; ++f)
#pragma unroll
    for (int s = 0; s < 8; ++s) {
      half8 bfrag = *reinterpret_cast<const half8*>(U1pk + (size_t)((s * 8 + f) * 64 + lane) * 8);
      acc[f] = __builtin_amdgcn_mfma_f32_16x16x32_f16(a[s], bfrag, acc[f], 0, 0, 0);
    }

#pragma unroll
  for (int f = 0; f < 8; ++f) {
    int col = f * 16 + r;
    float bv = bu1[col];
#pragma unroll
    for (int j = 0; j < 4; ++j) {
      int rl = g * 4 + j;
      float gv = gelu_exact(acc[f][j] + bv);
      *reinterpret_cast<_Float16*>(lbase + lds_swz(rl, col * 2)) = (_Float16)gv;
    }
  }

  half8 a2[4];
#pragma unroll
  for (int s = 0; s < 4; ++s)
    a2[s] = *reinterpret_cast<const half8*>(lbase + lds_swz(r, (s * 32 + g * 8) * 2));

  f32x4 acc2[8];
#pragma unroll
  for (int f = 0; f < 8; ++f) acc2[f] = zero;
#pragma unroll
  for (int f = 0; f < 8; ++f)
#pragma unroll
    for (int s = 0; s < 4; ++s) {
      half8 bfrag = *reinterpret_cast<const half8*>(U2pk + (size_t)((s * 8 + f) * 64 + lane) * 8);
      acc2[f] = __builtin_amdgcn_mfma_f32_16x16x32_f16(a2[s], bfrag, acc2[f], 0, 0, 0);
    }

#pragma unroll
  for (int f = 0; f < 8; ++f) {
    int col = f * 16 + r;
    float bv = bu2[col];
#pragma unroll
    for (int j = 0; j < 4; ++j) {
      int grow = row0 + g * 4 + j;
      if (grow < N_NODES)
        out[(size_t)grow * DIM + col] = gelu_exact(acc2[f][j] + bv);
    }
  }
}

extern "C" void kernel_launch(void* const* d_in, const int* in_sizes, int n_in,
                              void* d_out, int out_size, void* d_ws, size_t ws_size,
                              hipStream_t stream) {
  const float* x = (const float*)d_in[0];
  const int* edges = (const int*)d_in[1];
  const float* ew = (const float*)d_in[2];

  const int* node_idx = edges;            // edges[0, :]
  const int* nbr_idx = edges + N_EDGES;   // edges[1, :]

  char* wsp = (char*)d_ws;
  auto alloc = [&](size_t bytes) {
    char* p = wsp;
    wsp += (bytes + 255) & ~(size_t)255;
    return p;
  };
  _Float16* M = (_Float16*)alloc((size_t)N_NODES * DIM * 2);
  float* agg = (float*)alloc((size_t)N_NODES * DIM * 4);
  _Float16* W1pk = (_Float16*)alloc(128 * 128 * 2);
  _Float16* W2pk = (_Float16*)alloc(128 * 128 * 2);
  _Float16* U1pk = (_Float16*)alloc(256 * 128 * 2);
  _Float16* U2pk = (_Float16*)alloc(128 * 128 * 2);
  float* b1f = (float*)alloc(128 * 4);
  float* b2f = (float*)alloc(128 * 4);
  float* bu1 = (float*)alloc(128 * 4);
  float* bu2 = (float*)alloc(128 * 4);
  int* hist = (int*)alloc(N_NODES * 4);
  int* cursor = (int*)alloc(N_NODES * 4);
  int* row_start = (int*)alloc((N_NODES + 1) * 4);
  uint2* edge_s = (uint2*)alloc((size_t)N_EDGES * 8);

  FoldAll fa;
  fa.g[0] = (const float*)d_in[3];  fa.bb[0] = (const float*)d_in[4];
  fa.m[0] = (const float*)d_in[5];  fa.v[0] = (const float*)d_in[6];
  fa.W[0] = (const float*)d_in[7];  fa.bias[0] = (const float*)d_in[8];
  fa.g[1] = (const float*)d_in[9];  fa.bb[1] = (const float*)d_in[10];
  fa.m[1] = (const float*)d_in[11]; fa.v[1] = (const float*)d_in[12];
  fa.W[1] = (const float*)d_in[13]; fa.bias[1] = (const float*)d_in[14];
  fa.g[2] = (const float*)d_in[15]; fa.bb[2] = (const float*)d_in[16];
  fa.m[2] = (const float*)d_in[17]; fa.v[2] = (const float*)d_in[18];
  fa.W[2] = (const float*)d_in[19]; fa.bias[2] = (const float*)d_in[20];
  fa.g[3] = (const float*)d_in[21]; fa.bb[3] = (const float*)d_in[22];
  fa.m[3] = (const float*)d_in[23]; fa.v[3] = (const float*)d_in[24];
  fa.W[3] = (const float*)d_in[25]; fa.bias[3] = (const float*)d_in[26];
  fa.pk[0] = W1pk; fa.pk[1] = W2pk; fa.pk[2] = U1pk; fa.pk[3] = U2pk;
  fa.bf[0] = b1f; fa.bf[1] = b2f; fa.bf[2] = bu1; fa.bf[3] = bu2;
  fa.din[0] = 128; fa.din[1] = 128; fa.din[2] = 256; fa.din[3] = 128;
  fa.S[0] = 4; fa.S[1] = 4; fa.S[2] = 8; fa.S[3] = 4;

  fold_pack_kernel<<<54, 256, 0, stream>>>(fa, hist);

  msg_mfma_hist_kernel<<<MSG_MFMA_BLOCKS + HIST4_BLOCKS, 128, 0, stream>>>(
      x, W1pk, b1f, W2pk, b2f, M, node_idx, hist);

  scan_kernel<<<1, 256, 0, stream>>>(hist, row_start, cursor, N_NODES);
  scatter_kernel<<<SCAT_BLOCKS, 256, 0, stream>>>(node_idx, nbr_idx, ew, cursor, edge_s);
  spmm_kernel<<<N_NODES, 256, 0, stream>>>(row_start, edge_s, (const __half*)M, agg);

  update_mfma_kernel<<<MSG_MFMA_BLOCKS, 128, 0, stream>>>(
      x, agg, U1pk, bu1, U2pk, bu2, (float*)d_out);
}

// Round 5
// 184.598 us; speedup vs baseline: 1.2915x; 1.2915x over previous
//
#include <hip/hip_runtime.h>
#include <hip/hip_bf16.h>
#include <hip/hip_fp16.h>
#include <math.h>

#define N_NODES 10000
#define DIM 128
#define N_EDGES 640000
#define BN_EPS 1e-3f

#define MSG_MFMA_BLOCKS 313   // ceil(10000 / 32)
#define PART_BLOCKS 125       // 640000 / 5120
#define EDGES_PER_PART 5120   // 256 thr * 4 edges * 5 steps

typedef _Float16 half8 __attribute__((ext_vector_type(8)));
typedef float f32x4 __attribute__((ext_vector_type(4)));

__device__ __forceinline__ float gelu_exact(float x) {
  return 0.5f * x * (1.0f + erff(x * 0.70710678f));
}

// Swizzled per-wave LDS tile: [16 rows][128 cols] f16, row stride 256 B.
__device__ __forceinline__ int lds_swz(int row, int colbyte) {
  return ((row * 256 + colbyte) ^ ((row & 7) << 4));
}

struct FoldAll {
  const float* g[4];
  const float* bb[4];
  const float* m[4];
  const float* v[4];
  const float* W[4];
  const float* bias[4];
  _Float16* pk[4];
  float* bf[4];
  int din[4];
  int S[4];  // K/32
};

// grid = 44 blocks x 256 thr.
// blocks [0,40): pack W fragments (f16, B-frag layout, BN-scale folded).
// blocks [40,44): folded bias for param (blk-40): bf = bias + t @ W.
__global__ __launch_bounds__(256) void fold_pack_kernel(FoldAll fa) {
  int b = blockIdx.x, t = threadIdx.x;
  if (b >= 40) {
    int p = b - 40;
    int din = fa.din[p];
    const float* W = fa.W[p];
    __shared__ float t_sh[256];
    __shared__ float bpart[128];
    for (int k = t; k < din; k += 256) {
      float sc = fa.g[p][k] * rsqrtf(fa.v[p][k] + BN_EPS);
      t_sh[k] = fa.bb[p][k] - fa.m[p][k] * sc;
    }
    __syncthreads();
    int j = t & 127, kh = t >> 7;
    int half = din >> 1;
    float acc = 0.f;
    for (int k = kh * half; k < (kh + 1) * half; ++k)
      acc = fmaf(t_sh[k], W[k * 128 + j], acc);
    if (kh == 1) bpart[j] = acc;
    __syncthreads();
    if (kh == 0) fa.bf[p][j] = acc + bpart[j] + fa.bias[p][j];
    return;
  }
  int p, lf;
  if (b < 8)       { p = 0; lf = b * 256 + t; }
  else if (b < 16) { p = 1; lf = (b - 8) * 256 + t; }
  else if (b < 32) { p = 2; lf = (b - 16) * 256 + t; }
  else             { p = 3; lf = (b - 32) * 256 + t; }
  int S = fa.S[p];
  int l = lf & 63;
  int fs = lf >> 6;
  int f = fs & 7, s = fs >> 3;
  if (s >= S) return;
  const float* W = fa.W[p];
  const float* g = fa.g[p];
  const float* v = fa.v[p];
  int k0 = s * 32 + (l >> 4) * 8;
  int col = f * 16 + (l & 15);
  half8 h;
#pragma unroll
  for (int i = 0; i < 8; ++i) {
    int k = k0 + i;
    float sc = g[k] * rsqrtf(v[k] + BN_EPS);
    h[i] = (_Float16)(sc * W[k * 128 + col]);
  }
  *reinterpret_cast<half8*>(fa.pk[p] + (size_t)lf * 8) = h;
}

// Per-block LDS histogram -> full partial row (plain stores, no global atomics).
__global__ __launch_bounds__(256) void hist_part_kernel(
    const int* __restrict__ node_idx, int* __restrict__ part) {
  __shared__ int lh[N_NODES];
  int b = blockIdx.x, t = threadIdx.x;
  for (int i = t; i < N_NODES; i += 256) lh[i] = 0;
  __syncthreads();
  int base0 = b * EDGES_PER_PART;
#pragma unroll
  for (int s = 0; s < 5; ++s) {
    int base = base0 + s * 1024 + t * 4;
    int4 vv = *reinterpret_cast<const int4*>(&node_idx[base]);
    atomicAdd(&lh[vv.x], 1);
    atomicAdd(&lh[vv.y], 1);
    atomicAdd(&lh[vv.z], 1);
    atomicAdd(&lh[vv.w], 1);
  }
  __syncthreads();
  int* prow = part + (size_t)b * N_NODES;
  for (int i = t; i < N_NODES; i += 256) prow[i] = lh[i];
}

// Per bin: serial prefix over the 125 block-partials (in place -> exclusive
// offsets), total -> hist[bin]. Coalesced column access.
__global__ __launch_bounds__(256) void merge_kernel(int* __restrict__ part,
                                                    int* __restrict__ hist) {
  int bin = blockIdx.x * 256 + threadIdx.x;
  if (bin >= N_NODES) return;
  int sum = 0;
  for (int b = 0; b < PART_BLOCKS; ++b) {
    int* p = part + (size_t)b * N_NODES + bin;
    int c = *p;
    *p = sum;
    sum += c;
  }
  hist[bin] = sum;
}

// One block, 256 threads, each owns 40 contiguous elements.
__global__ __launch_bounds__(256) void scan_kernel(const int* __restrict__ hist,
                                                   int* __restrict__ row_start, int n) {
  const int PER = 40;
  __shared__ int sums[256];
  int t = threadIdx.x;
  int i0 = t * PER;
  int total = 0;
  for (int i = 0; i < PER; ++i) {
    int idx = i0 + i;
    total += (idx < n) ? hist[idx] : 0;
  }
  sums[t] = total;
  __syncthreads();
  for (int off = 1; off < 256; off <<= 1) {
    int v = (t >= off) ? sums[t - off] : 0;
    __syncthreads();
    sums[t] += v;
    __syncthreads();
  }
  int running = sums[t] - total;
  for (int i = 0; i < PER; ++i) {
    int idx = i0 + i;
    if (idx < n) {
      row_start[idx] = running;
      running += hist[idx];
    }
  }
  if (t == 255) row_start[n] = sums[255];
}

// Scatter with LDS-only atomics: cursor[d] = row_start[d] + part[b][d].
__global__ __launch_bounds__(256) void scatter_kernel(
    const int* __restrict__ node_idx, const int* __restrict__ nbr_idx,
    const float* __restrict__ ew, const int* __restrict__ row_start,
    const int* __restrict__ part, uint2* __restrict__ edge_s) {
  __shared__ int cur[N_NODES];
  int b = blockIdx.x, t = threadIdx.x;
  const int* prow = part + (size_t)b * N_NODES;
  for (int i = t; i < N_NODES; i += 256) cur[i] = row_start[i] + prow[i];
  __syncthreads();
  int base0 = b * EDGES_PER_PART;
#pragma unroll
  for (int s = 0; s < 5; ++s) {
    int base = base0 + s * 1024 + t * 4;
    int4 ni = *reinterpret_cast<const int4*>(&node_idx[base]);
    int4 nb = *reinterpret_cast<const int4*>(&nbr_idx[base]);
    float4 wv = *reinterpret_cast<const float4*>(&ew[base]);
    int p0 = atomicAdd(&cur[ni.x], 1);
    edge_s[p0] = make_uint2((unsigned)nb.x, __float_as_uint(wv.x));
    int p1 = atomicAdd(&cur[ni.y], 1);
    edge_s[p1] = make_uint2((unsigned)nb.y, __float_as_uint(wv.y));
    int p2 = atomicAdd(&cur[ni.z], 1);
    edge_s[p2] = make_uint2((unsigned)nb.z, __float_as_uint(wv.z));
    int p3 = atomicAdd(&cur[ni.w], 1);
    edge_s[p3] = make_uint2((unsigned)nb.w, __float_as_uint(wv.w));
  }
}

// Per-node message via f16 MFMA: 2 waves/block, 16 rows/wave, K=128.
__global__ __launch_bounds__(128) void msg_mfma_kernel(
    const float* __restrict__ x,
    const _Float16* __restrict__ W1pk, const float* __restrict__ b1f,
    const _Float16* __restrict__ W2pk, const float* __restrict__ b2f,
    _Float16* __restrict__ M) {
  __shared__ char lds_raw[2 * 4096];
  int t = threadIdx.x;
  int wid = t >> 6, lane = t & 63;
  int r = lane & 15, g = lane >> 4;
  int row0 = blockIdx.x * 32 + wid * 16;
  char* lbase = lds_raw + wid * 4096;

  int arow = row0 + r;
  if (arow > N_NODES - 1) arow = N_NODES - 1;
  const float* xp = x + (size_t)arow * DIM;

  half8 a[4];
#pragma unroll
  for (int s = 0; s < 4; ++s) {
    float4 lo = *reinterpret_cast<const float4*>(xp + s * 32 + g * 8);
    float4 hi = *reinterpret_cast<const float4*>(xp + s * 32 + g * 8 + 4);
    half8 h;
    h[0] = (_Float16)lo.x; h[1] = (_Float16)lo.y; h[2] = (_Float16)lo.z; h[3] = (_Float16)lo.w;
    h[4] = (_Float16)hi.x; h[5] = (_Float16)hi.y; h[6] = (_Float16)hi.z; h[7] = (_Float16)hi.w;
    a[s] = h;
  }

  f32x4 zero = {0.f, 0.f, 0.f, 0.f};
  f32x4 acc[8];
#pragma unroll
  for (int f = 0; f < 8; ++f) acc[f] = zero;
#pragma unroll
  for (int f = 0; f < 8; ++f)
#pragma unroll
    for (int s = 0; s < 4; ++s) {
      half8 bfrag = *reinterpret_cast<const half8*>(W1pk + (size_t)((s * 8 + f) * 64 + lane) * 8);
      acc[f] = __builtin_amdgcn_mfma_f32_16x16x32_f16(a[s], bfrag, acc[f], 0, 0, 0);
    }

#pragma unroll
  for (int f = 0; f < 8; ++f) {
    int col = f * 16 + r;
    float bv = b1f[col];
#pragma unroll
    for (int j = 0; j < 4; ++j) {
      int rl = g * 4 + j;
      float gv = gelu_exact(acc[f][j] + bv);
      *reinterpret_cast<_Float16*>(lbase + lds_swz(rl, col * 2)) = (_Float16)gv;
    }
  }

  half8 a2[4];
#pragma unroll
  for (int s = 0; s < 4; ++s)
    a2[s] = *reinterpret_cast<const half8*>(lbase + lds_swz(r, (s * 32 + g * 8) * 2));

  f32x4 acc2[8];
#pragma unroll
  for (int f = 0; f < 8; ++f) acc2[f] = zero;
#pragma unroll
  for (int f = 0; f < 8; ++f)
#pragma unroll
    for (int s = 0; s < 4; ++s) {
      half8 bfrag = *reinterpret_cast<const half8*>(W2pk + (size_t)((s * 8 + f) * 64 + lane) * 8);
      acc2[f] = __builtin_amdgcn_mfma_f32_16x16x32_f16(a2[s], bfrag, acc2[f], 0, 0, 0);
    }

#pragma unroll
  for (int f = 0; f < 8; ++f) {
    int col = f * 16 + r;
    float bv = b2f[col];
#pragma unroll
    for (int j = 0; j < 4; ++j) {
      int grow = row0 + g * 4 + j;
      if (grow < N_NODES)
        M[(size_t)grow * DIM + col] = (_Float16)gelu_exact(acc2[f][j] + bv);
    }
  }
}

// agg[i] = (sum over CSR row i of w_e * M[nbr_e]) / max(cnt,1)
__global__ __launch_bounds__(256) void spmm_kernel(
    const int* __restrict__ row_start, const uint2* __restrict__ edge_s,
    const __half* __restrict__ M, float* __restrict__ agg) {
  __shared__ float4 red4[8][32];
  int i = blockIdx.x;
  int t = threadIdx.x;
  int cg = t & 31;
  int slice = t >> 5;
  int s = row_start[i];
  int e_end = row_start[i + 1];

  float a0 = 0.f, a1 = 0.f, a2 = 0.f, a3 = 0.f;
  int e = s + slice;
  if (e < e_end) {
    uint2 pk = edge_s[e];
    for (; e < e_end; e += 8) {
      int en = e + 8;
      uint2 nxt = (en < e_end) ? edge_s[en] : pk;
      unsigned nbr = pk.x;
      float w = __uint_as_float(pk.y);
      uint2 raw = *reinterpret_cast<const uint2*>(M + (size_t)nbr * DIM + cg * 4);
      __half2 h01 = *reinterpret_cast<__half2*>(&raw.x);
      __half2 h23 = *reinterpret_cast<__half2*>(&raw.y);
      float2 f01 = __half22float2(h01);
      float2 f23 = __half22float2(h23);
      a0 = fmaf(w, f01.x, a0);
      a1 = fmaf(w, f01.y, a1);
      a2 = fmaf(w, f23.x, a2);
      a3 = fmaf(w, f23.y, a3);
      pk = nxt;
    }
  }
  red4[slice][cg] = make_float4(a0, a1, a2, a3);
  __syncthreads();

  if (t < 128) {
    const float* redf = (const float*)red4;
    float acc = 0.f;
#pragma unroll
    for (int sl = 0; sl < 8; ++sl) acc += redf[sl * 128 + t];
    int cnt = e_end - s;
    agg[(size_t)i * DIM + t] = acc / (float)(cnt > 0 ? cnt : 1);
  }
}

// update: out = gelu(gelu([x,agg]@U1+bu1)@U2+bu2), f16 MFMA, K1=256.
__global__ __launch_bounds__(128) void update_mfma_kernel(
    const float* __restrict__ x, const float* __restrict__ agg,
    const _Float16* __restrict__ U1pk, const float* __restrict__ bu1,
    const _Float16* __restrict__ U2pk, const float* __restrict__ bu2,
    float* __restrict__ out) {
  __shared__ char lds_raw[2 * 4096];
  int t = threadIdx.x;
  int wid = t >> 6, lane = t & 63;
  int r = lane & 15, g = lane >> 4;
  int row0 = blockIdx.x * 32 + wid * 16;
  char* lbase = lds_raw + wid * 4096;

  int arow = row0 + r;
  if (arow > N_NODES - 1) arow = N_NODES - 1;
  const float* xp = x + (size_t)arow * DIM;
  const float* ap = agg + (size_t)arow * DIM;

  half8 a[8];
#pragma unroll
  for (int s = 0; s < 8; ++s) {
    const float* src = (s < 4) ? (xp + s * 32 + g * 8) : (ap + (s - 4) * 32 + g * 8);
    float4 lo = *reinterpret_cast<const float4*>(src);
    float4 hi = *reinterpret_cast<const float4*>(src + 4);
    half8 h;
    h[0] = (_Float16)lo.x; h[1] = (_Float16)lo.y; h[2] = (_Float16)lo.z; h[3] = (_Float16)lo.w;
    h[4] = (_Float16)hi.x; h[5] = (_Float16)hi.y; h[6] = (_Float16)hi.z; h[7] = (_Float16)hi.w;
    a[s] = h;
  }

  f32x4 zero = {0.f, 0.f, 0.f, 0.f};
  f32x4 acc[8];
#pragma unroll
  for (int f = 0; f < 8; ++f) acc[f] = zero;
#pragma unroll
  for (int f = 0; f < 8; ++f)
#pragma unroll
    for (int s = 0; s < 8; ++s) {
      half8 bfrag = *reinterpret_cast<const half8*>(U1pk + (size_t)((s * 8 + f) * 64 + lane) * 8);
      acc[f] = __builtin_amdgcn_mfma_f32_16x16x32_f16(a[s], bfrag, acc[f], 0, 0, 0);
    }

#pragma unroll
  for (int f = 0; f < 8; ++f) {
    int col = f * 16 + r;
    float bv = bu1[col];
#pragma unroll
    for (int j = 0; j < 4; ++j) {
      int rl = g * 4 + j;
      float gv = gelu_exact(acc[f][j] + bv);
      *reinterpret_cast<_Float16*>(lbase + lds_swz(rl, col * 2)) = (_Float16)gv;
    }
  }

  half8 a2[4];
#pragma unroll
  for (int s = 0; s < 4; ++s)
    a2[s] = *reinterpret_cast<const half8*>(lbase + lds_swz(r, (s * 32 + g * 8) * 2));

  f32x4 acc2[8];
#pragma unroll
  for (int f = 0; f < 8; ++f) acc2[f] = zero;
#pragma unroll
  for (int f = 0; f < 8; ++f)
#pragma unroll
    for (int s = 0; s < 4; ++s) {
      half8 bfrag = *reinterpret_cast<const half8*>(U2pk + (size_t)((s * 8 + f) * 64 + lane) * 8);
      acc2[f] = __builtin_amdgcn_mfma_f32_16x16x32_f16(a2[s], bfrag, acc2[f], 0, 0, 0);
    }

#pragma unroll
  for (int f = 0; f < 8; ++f) {
    int col = f * 16 + r;
    float bv = bu2[col];
#pragma unroll
    for (int j = 0; j < 4; ++j) {
      int grow = row0 + g * 4 + j;
      if (grow < N_NODES)
        out[(size_t)grow * DIM + col] = gelu_exact(acc2[f][j] + bv);
    }
  }
}

extern "C" void kernel_launch(void* const* d_in, const int* in_sizes, int n_in,
                              void* d_out, int out_size, void* d_ws, size_t ws_size,
                              hipStream_t stream) {
  const float* x = (const float*)d_in[0];
  const int* edges = (const int*)d_in[1];
  const float* ew = (const float*)d_in[2];

  const int* node_idx = edges;            // edges[0, :]
  const int* nbr_idx = edges + N_EDGES;   // edges[1, :]

  char* wsp = (char*)d_ws;
  auto alloc = [&](size_t bytes) {
    char* p = wsp;
    wsp += (bytes + 255) & ~(size_t)255;
    return p;
  };
  _Float16* M = (_Float16*)alloc((size_t)N_NODES * DIM * 2);
  float* agg = (float*)alloc((size_t)N_NODES * DIM * 4);
  _Float16* W1pk = (_Float16*)alloc(128 * 128 * 2);
  _Float16* W2pk = (_Float16*)alloc(128 * 128 * 2);
  _Float16* U1pk = (_Float16*)alloc(256 * 128 * 2);
  _Float16* U2pk = (_Float16*)alloc(128 * 128 * 2);
  float* b1f = (float*)alloc(128 * 4);
  float* b2f = (float*)alloc(128 * 4);
  float* bu1 = (float*)alloc(128 * 4);
  float* bu2 = (float*)alloc(128 * 4);
  int* hist = (int*)alloc(N_NODES * 4);
  int* row_start = (int*)alloc((N_NODES + 1) * 4);
  int* part = (int*)alloc((size_t)PART_BLOCKS * N_NODES * 4);
  uint2* edge_s = (uint2*)alloc((size_t)N_EDGES * 8);

  FoldAll fa;
  fa.g[0] = (const float*)d_in[3];  fa.bb[0] = (const float*)d_in[4];
  fa.m[0] = (const float*)d_in[5];  fa.v[0] = (const float*)d_in[6];
  fa.W[0] = (const float*)d_in[7];  fa.bias[0] = (const float*)d_in[8];
  fa.g[1] = (const float*)d_in[9];  fa.bb[1] = (const float*)d_in[10];
  fa.m[1] = (const float*)d_in[11]; fa.v[1] = (const float*)d_in[12];
  fa.W[1] = (const float*)d_in[13]; fa.bias[1] = (const float*)d_in[14];
  fa.g[2] = (const float*)d_in[15]; fa.bb[2] = (const float*)d_in[16];
  fa.m[2] = (const float*)d_in[17]; fa.v[2] = (const float*)d_in[18];
  fa.W[2] = (const float*)d_in[19]; fa.bias[2] = (const float*)d_in[20];
  fa.g[3] = (const float*)d_in[21]; fa.bb[3] = (const float*)d_in[22];
  fa.m[3] = (const float*)d_in[23]; fa.v[3] = (const float*)d_in[24];
  fa.W[3] = (const float*)d_in[25]; fa.bias[3] = (const float*)d_in[26];
  fa.pk[0] = W1pk; fa.pk[1] = W2pk; fa.pk[2] = U1pk; fa.pk[3] = U2pk;
  fa.bf[0] = b1f; fa.bf[1] = b2f; fa.bf[2] = bu1; fa.bf[3] = bu2;
  fa.din[0] = 128; fa.din[1] = 128; fa.din[2] = 256; fa.din[3] = 128;
  fa.S[0] = 4; fa.S[1] = 4; fa.S[2] = 8; fa.S[3] = 4;

  fold_pack_kernel<<<44, 256, 0, stream>>>(fa);
  hist_part_kernel<<<PART_BLOCKS, 256, 0, stream>>>(node_idx, part);
  msg_mfma_kernel<<<MSG_MFMA_BLOCKS, 128, 0, stream>>>(x, W1pk, b1f, W2pk, b2f, M);
  merge_kernel<<<(N_NODES + 255) / 256, 256, 0, stream>>>(part, hist);
  scan_kernel<<<1, 256, 0, stream>>>(hist, row_start, N_NODES);
  scatter_kernel<<<PART_BLOCKS, 256, 0, stream>>>(node_idx, nbr_idx, ew, row_start, part, edge_s);
  spmm_kernel<<<N_NODES, 256, 0, stream>>>(row_start, edge_s, (const __half*)M, agg);
  update_mfma_kernel<<<MSG_MFMA_BLOCKS, 128, 0, stream>>>(
      x, agg, U1pk, bu1, U2pk, bu2, (float*)d_out);
}